// Round 2
// baseline (756.281 us; speedup 1.0000x reference)
//
#include <hip/hip_runtime.h>
#include <math.h>

#define BB 512
#define DD 16
#define NN 64
#define MM 32
#define RR 32
#define CC 10
#define BBLK 16   // b's per workgroup in chain_seg_kernel
#define SS 2      // chain segments (d 0..7 | d 8..15)

// ---------------------------------------------------------------------------
// Kernel 1: feat[b,d,m] = sum_n tensor[b,d,n] * W[n,m] + bias[m]
// ---------------------------------------------------------------------------
__global__ void feat_kernel(const float* __restrict__ tensor,
                            const float* __restrict__ W,
                            const float* __restrict__ bias,
                            float* __restrict__ feat) {
    int t  = blockIdx.x * blockDim.x + threadIdx.x;   // 0 .. B*D*M-1
    int m  = t & (MM - 1);
    int bd = t >> 5;
    const float* tp = tensor + bd * NN;
    float acc = bias[m];
#pragma unroll
    for (int n = 0; n < NN; ++n) acc += tp[n] * W[n * MM + m];
    feat[t] = acc;
}

// ---------------------------------------------------------------------------
// Kernel 2: per (c, b-block of 16, segment s): build cores on the fly and
// multiply the segment's 8 cores. Writes the 32x32 partial product per (c,b,s)
// to ws. Grid = C * (B/BBLK) * SS = 640 WGs (vs 320 before: occupancy was the
// round-1 bottleneck — 7.7% occupancy, 19.6% VALUBusy).
// ---------------------------------------------------------------------------
__global__ __launch_bounds__(256) void chain_seg_kernel(
    const float* __restrict__ feat,   // [B][D][M]
    const float* __restrict__ G,      // [C][D][R][M][R]
    float* __restrict__ segP)         // [C][B][SS][R][R]
{
    __shared__ __align__(16) float feat_sT[MM][20];           // [m][b], padded
    __shared__ __align__(16) float core_s[BBLK][16 * RR + 4]; // half-chunk

    const int bid = blockIdx.x;          // 0..639
    const int c   = bid % CC;
    const int rem = bid / CC;            // 0..63
    const int s   = rem & (SS - 1);
    const int b0  = (rem >> 1) * BBLK;
    const int d0  = s * (DD / SS);
    const int d1  = d0 + (DD / SS);
    const int t   = threadIdx.x;

    // phase-1 indices
    const int j  = t & 31;
    const int ig = t >> 5;               // 0..7
    // phase-2 indices
    const int b2 = t >> 4;               // 0..15
    const int rp = t & 15;
    const int i0 = rp * 2, i1 = rp * 2 + 1;
    // feat-staging indices (coalesced: lane-consecutive m)
    const int fm = t & 31;
    const int fb = t >> 5;               // 0..7

    float p0[RR], p1[RR], q0[RR], q1[RR];

    for (int d = d0; d < d1; ++d) {
        __syncthreads();   // prev-iter P1 feat reads done; safe to restage
        // stage feat_sT[m][b] for this d — coalesced over m
        feat_sT[fm][fb]     = feat[(b0 + fb)     * (DD * MM) + d * MM + fm];
        feat_sT[fm][fb + 8] = feat[(b0 + fb + 8) * (DD * MM) + d * MM + fm];

        if (d > d0) {
#pragma unroll
            for (int x = 0; x < RR; ++x) { q0[x] = 0.f; q1[x] = 0.f; }
        }
        const float* Gd = G + (size_t)(c * DD + d) * (RR * MM * RR);

#pragma unroll
        for (int h = 0; h < 2; ++h) {
            __syncthreads();  // feat staged / prev half's P2 reads done
            // ---- Phase 1: core rows i = h*16 + ig*2 + {0,1}, all 16 b ----
            {
                float a0[BBLK], a1[BBLK];
#pragma unroll
                for (int b = 0; b < BBLK; ++b) { a0[b] = 0.f; a1[b] = 0.f; }
                const int irow = h * 16 + ig * 2;
                const float* Gp0 = Gd + irow * (MM * RR) + j;
                const float* Gp1 = Gp0 + MM * RR;
#pragma unroll 4
                for (int m = 0; m < MM; ++m) {
                    float g0 = Gp0[m * RR];
                    float g1 = Gp1[m * RR];
                    const float4* fv =
                        reinterpret_cast<const float4*>(&feat_sT[m][0]);
#pragma unroll
                    for (int v = 0; v < 4; ++v) {
                        float4 f = fv[v];
                        a0[v*4+0] += g0 * f.x; a0[v*4+1] += g0 * f.y;
                        a0[v*4+2] += g0 * f.z; a0[v*4+3] += g0 * f.w;
                        a1[v*4+0] += g1 * f.x; a1[v*4+1] += g1 * f.y;
                        a1[v*4+2] += g1 * f.z; a1[v*4+3] += g1 * f.w;
                    }
                }
                const int kk0 = ig * 2;
#pragma unroll
                for (int b = 0; b < BBLK; ++b) {
                    core_s[b][kk0 * RR + j]       = a0[b];
                    core_s[b][(kk0 + 1) * RR + j] = a1[b];
                }
            }
            __syncthreads();
            // ---- Phase 2 ----
            if (d == d0) {
                if ((i0 >> 4) == h) {
                    const float4* r0 = reinterpret_cast<const float4*>(
                        &core_s[b2][(i0 & 15) * RR]);
                    const float4* r1 = reinterpret_cast<const float4*>(
                        &core_s[b2][(i1 & 15) * RR]);
#pragma unroll
                    for (int v = 0; v < 8; ++v) {
                        float4 x0 = r0[v], x1 = r1[v];
                        p0[v*4+0] = x0.x; p0[v*4+1] = x0.y;
                        p0[v*4+2] = x0.z; p0[v*4+3] = x0.w;
                        p1[v*4+0] = x1.x; p1[v*4+1] = x1.y;
                        p1[v*4+2] = x1.z; p1[v*4+3] = x1.w;
                    }
                }
            } else {
#pragma unroll
                for (int kk = 0; kk < 16; ++kk) {
                    const float a0 = p0[h * 16 + kk];
                    const float a1 = p1[h * 16 + kk];
                    const float4* cv =
                        reinterpret_cast<const float4*>(&core_s[b2][kk * RR]);
#pragma unroll
                    for (int v = 0; v < 8; ++v) {
                        float4 cc = cv[v];
                        q0[v*4+0] += a0 * cc.x; q0[v*4+1] += a0 * cc.y;
                        q0[v*4+2] += a0 * cc.z; q0[v*4+3] += a0 * cc.w;
                        q1[v*4+0] += a1 * cc.x; q1[v*4+1] += a1 * cc.y;
                        q1[v*4+2] += a1 * cc.z; q1[v*4+3] += a1 * cc.w;
                    }
                }
            }
        }
        if (d > d0) {
#pragma unroll
            for (int x = 0; x < RR; ++x) { p0[x] = q0[x]; p1[x] = q1[x]; }
        }
    }

    // write segment product: thread owns rows i0, i1 of prod for b = b0+b2
    {
        float* dst0 = segP +
            ((((size_t)c * BB + (b0 + b2)) * SS + s) * RR + i0) * RR;
        float* dst1 = dst0 + RR;
        float4* v0 = reinterpret_cast<float4*>(dst0);
        float4* v1 = reinterpret_cast<float4*>(dst1);
#pragma unroll
        for (int v = 0; v < 8; ++v) {
            v0[v] = make_float4(p0[v*4+0], p0[v*4+1], p0[v*4+2], p0[v*4+3]);
            v1[v] = make_float4(p1[v*4+0], p1[v*4+1], p1[v*4+2], p1[v*4+3]);
        }
    }
}

// ---------------------------------------------------------------------------
// Kernel 3: per b: logits[c] = trace(P0 @ P1) = sum_ij P0[i][j]*P1[j][i],
// then log-softmax. One wave per b (4 waves / 256-thread block).
// ---------------------------------------------------------------------------
__global__ __launch_bounds__(256) void trace_lsm_kernel(
    const float* __restrict__ segP,   // [C][B][SS][R][R]
    float* __restrict__ out)          // [B][C]
{
    const int t    = threadIdx.x;
    const int b    = blockIdx.x * 4 + (t >> 6);
    const int lane = t & 63;
    const int i    = lane & 31;
    const int jh   = lane >> 5;       // 0 or 1

    float tr[CC];
#pragma unroll
    for (int c = 0; c < CC; ++c) {
        const float* P0 = segP + (((size_t)c * BB + b) * SS + 0) * (RR * RR);
        const float* P1 = segP + (((size_t)c * BB + b) * SS + 1) * (RR * RR);
        float acc = 0.f;
#pragma unroll
        for (int jj = 0; jj < 16; ++jj) {
            int jcol = jh * 16 + jj;
            acc += P0[i * RR + jcol] * P1[jcol * RR + i];
        }
        tr[c] = acc;
    }
    // reduce each tr[c] across the 64-lane wave
#pragma unroll
    for (int c = 0; c < CC; ++c) {
#pragma unroll
        for (int off = 32; off > 0; off >>= 1)
            tr[c] += __shfl_down(tr[c], off);
    }
    if (lane == 0) {
        float mx = -1e30f;
#pragma unroll
        for (int c = 0; c < CC; ++c) mx = fmaxf(mx, tr[c]);
        float ssum = 0.f;
#pragma unroll
        for (int c = 0; c < CC; ++c) ssum += expf(tr[c] - mx);
        float ls = logf(ssum);
#pragma unroll
        for (int c = 0; c < CC; ++c) out[b * CC + c] = tr[c] - mx - ls;
    }
}

// ---------------------------------------------------------------------------
extern "C" void kernel_launch(void* const* d_in, const int* in_sizes, int n_in,
                              void* d_out, int out_size, void* d_ws, size_t ws_size,
                              hipStream_t stream) {
    const float* tensor = (const float*)d_in[0];
    const float* W      = (const float*)d_in[1];
    const float* bias   = (const float*)d_in[2];
    const float* G      = (const float*)d_in[3];
    float* out  = (float*)d_out;
    float* feat = (float*)d_ws;                    // B*D*M = 262144 floats (1 MB)
    float* segP = feat + BB * DD * MM;             // C*B*SS*R*R = 10.5M floats (42 MB)

    feat_kernel<<<(BB * DD * MM) / 256, 256, 0, stream>>>(tensor, W, bias, feat);
    chain_seg_kernel<<<CC * (BB / BBLK) * SS, 256, 0, stream>>>(feat, G, segP);
    trace_lsm_kernel<<<BB / 4, 256, 0, stream>>>(segP, out);
}

// Round 3
// 373.007 us; speedup vs baseline: 2.0275x; 2.0275x over previous
//
#include <hip/hip_runtime.h>
#include <math.h>

#define BB 512
#define DD 16
#define NN 64
#define MM 32
#define RR 32
#define CC 10
#define BBLK 8    // b's per workgroup in chain_seg_kernel
#define SS 2      // chain segments (d 0..7 | d 8..15)
#define RSTR 36   // padded row stride (words) in core_s: 36*4=144B, 16B-aligned,
                  // makes phase-1 b128 writes and all reads <=2-way (free)
#define SB (RR * RSTR)   // 1152 words per b

// ---------------------------------------------------------------------------
// Kernel 1: feat[b,d,m] = sum_n tensor[b,d,n] * W[n,m] + bias[m]
// ---------------------------------------------------------------------------
__global__ void feat_kernel(const float* __restrict__ tensor,
                            const float* __restrict__ W,
                            const float* __restrict__ bias,
                            float* __restrict__ feat) {
    int t  = blockIdx.x * blockDim.x + threadIdx.x;   // 0 .. B*D*M-1
    int m  = t & (MM - 1);
    int bd = t >> 5;
    const float* tp = tensor + bd * NN;
    float acc = bias[m];
#pragma unroll
    for (int n = 0; n < NN; ++n) acc += tp[n] * W[n * MM + m];
    feat[t] = acc;
}

// ---------------------------------------------------------------------------
// Kernel 2: per (c, b-block of 8, segment s): build the full 32x32 core for
// all 8 b in LDS (one shot, no h-halving), chain-multiply 8 cores, write the
// 32x32 segment product to ws.
//   Grid = SS * CC * (B/BBLK) = 1280 blocks; __launch_bounds__(256,4) caps
//   VGPR at 128 -> 4 blocks/CU resident (round-2 lesson: 176 VGPR -> 2/CU).
//   Exactly 2 __syncthreads per d (vs 5 in rounds 1-2).
// Phase-1: thread (jq=t&7, i=t>>3) computes core[b][i][jq*4..+3] for 8 b,
//          G read as float4 (fully coalesced), write as ds_write_b128.
// Phase-2: thread (b2=t>>5, rp=t&31) owns prod row rp of b2; core rows read
//          as b128 broadcasts (2 distinct addrs/wave = conflict-free).
// ---------------------------------------------------------------------------
__global__ __launch_bounds__(256, 4) void chain_seg_kernel(
    const float* __restrict__ feat,   // [B][D][M]
    const float* __restrict__ G,      // [C][D][R][M][R]
    float* __restrict__ segP)         // [C][B][SS][R][R]
{
    __shared__ __align__(16) float feat_sT[MM][BBLK];   // [m][b], 1 KB
    __shared__ __align__(16) float core_s[BBLK][SB];    // 36.9 KB

    const int bid = blockIdx.x;            // 0..1279
    const int s   = bid & 1;
    const int c   = (bid >> 1) % CC;
    const int b0  = (bid / (2 * CC)) * BBLK;
    const int d0  = s * (DD / SS);
    const int t   = threadIdx.x;

    // phase-1 indices
    const int jq = t & 7;                  // j = jq*4 + 0..3
    const int ir = t >> 3;                 // row 0..31
    // phase-2 indices
    const int b2 = t >> 5;                 // 0..7
    const int rp = t & 31;                 // prod row
    // feat staging indices (coalesced over m)
    const int fm = t & 31;
    const int fb = t >> 5;

    float p[RR];

    for (int dd = 0; dd < DD / SS; ++dd) {
        const int d = d0 + dd;
        // stage feat for this d (256 elements, 1 per thread)
        feat_sT[fm][fb] = feat[(b0 + fb) * (DD * MM) + d * MM + fm];
        __syncthreads();   // feat ready; core_s free (prev phase-2 done)

        // ---- Phase 1: full core for 8 b ----
        {
            float a0[BBLK], a1[BBLK], a2[BBLK], a3[BBLK];
#pragma unroll
            for (int b = 0; b < BBLK; ++b) {
                a0[b] = 0.f; a1[b] = 0.f; a2[b] = 0.f; a3[b] = 0.f;
            }
            const float* Gp = G + (size_t)(c * DD + d) * (RR * MM * RR)
                                + ir * (MM * RR) + jq * 4;
#pragma unroll 8
            for (int m = 0; m < MM; ++m) {
                const float4 g  = *reinterpret_cast<const float4*>(Gp + m * RR);
                const float4 f0 = *reinterpret_cast<const float4*>(&feat_sT[m][0]);
                const float4 f1 = *reinterpret_cast<const float4*>(&feat_sT[m][4]);
                a0[0] += g.x * f0.x; a0[1] += g.x * f0.y;
                a0[2] += g.x * f0.z; a0[3] += g.x * f0.w;
                a0[4] += g.x * f1.x; a0[5] += g.x * f1.y;
                a0[6] += g.x * f1.z; a0[7] += g.x * f1.w;
                a1[0] += g.y * f0.x; a1[1] += g.y * f0.y;
                a1[2] += g.y * f0.z; a1[3] += g.y * f0.w;
                a1[4] += g.y * f1.x; a1[5] += g.y * f1.y;
                a1[6] += g.y * f1.z; a1[7] += g.y * f1.w;
                a2[0] += g.z * f0.x; a2[1] += g.z * f0.y;
                a2[2] += g.z * f0.z; a2[3] += g.z * f0.w;
                a2[4] += g.z * f1.x; a2[5] += g.z * f1.y;
                a2[6] += g.z * f1.z; a2[7] += g.z * f1.w;
                a3[0] += g.w * f0.x; a3[1] += g.w * f0.y;
                a3[2] += g.w * f0.z; a3[3] += g.w * f0.w;
                a3[4] += g.w * f1.x; a3[5] += g.w * f1.y;
                a3[6] += g.w * f1.z; a3[7] += g.w * f1.w;
            }
#pragma unroll
            for (int b = 0; b < BBLK; ++b) {
                *reinterpret_cast<float4*>(&core_s[b][ir * RSTR + jq * 4]) =
                    make_float4(a0[b], a1[b], a2[b], a3[b]);
            }
        }
        __syncthreads();   // core ready

        // ---- Phase 2 ----
        if (dd == 0) {
            const float4* r = reinterpret_cast<const float4*>(
                &core_s[b2][rp * RSTR]);
#pragma unroll
            for (int v = 0; v < 8; ++v) {
                float4 x = r[v];
                p[v*4+0] = x.x; p[v*4+1] = x.y; p[v*4+2] = x.z; p[v*4+3] = x.w;
            }
        } else {
            float q[RR];
#pragma unroll
            for (int x = 0; x < RR; ++x) q[x] = 0.f;
#pragma unroll 8
            for (int kk = 0; kk < RR; ++kk) {
                const float a = p[kk];
                const float4* cv = reinterpret_cast<const float4*>(
                    &core_s[b2][kk * RSTR]);
#pragma unroll
                for (int v = 0; v < 8; ++v) {
                    float4 cc = cv[v];
                    q[v*4+0] += a * cc.x; q[v*4+1] += a * cc.y;
                    q[v*4+2] += a * cc.z; q[v*4+3] += a * cc.w;
                }
            }
#pragma unroll
            for (int x = 0; x < RR; ++x) p[x] = q[x];
        }
    }

    // write segment product: thread owns row rp of b = b0+b2
    {
        float* dst = segP +
            ((((size_t)c * BB + (b0 + b2)) * SS + s) * RR + rp) * RR;
        float4* v4 = reinterpret_cast<float4*>(dst);
#pragma unroll
        for (int v = 0; v < 8; ++v)
            v4[v] = make_float4(p[v*4+0], p[v*4+1], p[v*4+2], p[v*4+3]);
    }
}

// ---------------------------------------------------------------------------
// Kernel 3: per b: logits[c] = trace(P0 @ P1) = sum_ij P0[i][j]*P1[j][i],
// then log-softmax. One wave per b (4 waves / 256-thread block).
// ---------------------------------------------------------------------------
__global__ __launch_bounds__(256) void trace_lsm_kernel(
    const float* __restrict__ segP,   // [C][B][SS][R][R]
    float* __restrict__ out)          // [B][C]
{
    const int t    = threadIdx.x;
    const int b    = blockIdx.x * 4 + (t >> 6);
    const int lane = t & 63;
    const int i    = lane & 31;
    const int jh   = lane >> 5;       // 0 or 1

    float tr[CC];
#pragma unroll
    for (int c = 0; c < CC; ++c) {
        const float* P0 = segP + (((size_t)c * BB + b) * SS + 0) * (RR * RR);
        const float* P1 = segP + (((size_t)c * BB + b) * SS + 1) * (RR * RR);
        float acc = 0.f;
#pragma unroll
        for (int jj = 0; jj < 16; ++jj) {
            int jcol = jh * 16 + jj;
            acc += P0[i * RR + jcol] * P1[jcol * RR + i];
        }
        tr[c] = acc;
    }
#pragma unroll
    for (int c = 0; c < CC; ++c) {
#pragma unroll
        for (int off = 32; off > 0; off >>= 1)
            tr[c] += __shfl_down(tr[c], off);
    }
    if (lane == 0) {
        float mx = -1e30f;
#pragma unroll
        for (int c = 0; c < CC; ++c) mx = fmaxf(mx, tr[c]);
        float ssum = 0.f;
#pragma unroll
        for (int c = 0; c < CC; ++c) ssum += expf(tr[c] - mx);
        float ls = logf(ssum);
#pragma unroll
        for (int c = 0; c < CC; ++c) out[b * CC + c] = tr[c] - mx - ls;
    }
}

// ---------------------------------------------------------------------------
extern "C" void kernel_launch(void* const* d_in, const int* in_sizes, int n_in,
                              void* d_out, int out_size, void* d_ws, size_t ws_size,
                              hipStream_t stream) {
    const float* tensor = (const float*)d_in[0];
    const float* W      = (const float*)d_in[1];
    const float* bias   = (const float*)d_in[2];
    const float* G      = (const float*)d_in[3];
    float* out  = (float*)d_out;
    float* feat = (float*)d_ws;                    // B*D*M = 262144 floats (1 MB)
    float* segP = feat + BB * DD * MM;             // C*B*SS*R*R floats (42 MB)

    feat_kernel<<<(BB * DD * MM) / 256, 256, 0, stream>>>(tensor, W, bias, feat);
    chain_seg_kernel<<<SS * CC * (BB / BBLK), 256, 0, stream>>>(feat, G, segP);
    trace_lsm_kernel<<<BB / 4, 256, 0, stream>>>(segP, out);
}

// Round 4
// 236.112 us; speedup vs baseline: 3.2031x; 1.5798x over previous
//
#include <hip/hip_runtime.h>
#include <math.h>

#define BB 512
#define DD 16
#define NN 64
#define MM 32
#define RR 32
#define CC 10
#define BBLK 8           // b's per chain block (= waves per block)
#define RSTR 36          // dword stride of a core/scratch row (16B-aligned rows)
#define BREG (RR * RSTR) // 1152 dwords per b region

typedef _Float16 v8h __attribute__((ext_vector_type(8)));
typedef float v4f __attribute__((ext_vector_type(4)));

union U4 { unsigned int u[4]; v8h h; };

// split fp32 -> (hi fp16, lo fp16) packed in one dword: hi in [31:16], lo in [15:0]
__device__ __forceinline__ unsigned int split_pack(float x) {
    _Float16 h = (_Float16)x;
    _Float16 l = (_Float16)(x - (float)h);
    unsigned int hb = (unsigned int)__builtin_bit_cast(unsigned short, h);
    unsigned int lb = (unsigned int)__builtin_bit_cast(unsigned short, l);
    return (hb << 16) | lb;
}

// from packed dwords (u_even, u_odd) build fp16-pair dwords for hi and lo planes
__device__ __forceinline__ unsigned int pair_h(unsigned int ue, unsigned int uo) {
    return __builtin_amdgcn_perm(uo, ue, 0x07060302u); // [uo.h | ue.h]
}
__device__ __forceinline__ unsigned int pair_l(unsigned int ue, unsigned int uo) {
    return __builtin_amdgcn_perm(uo, ue, 0x05040100u); // [uo.l | ue.l]
}

__device__ __forceinline__ void unpack8(const unsigned int* u, U4* fh, U4* fl) {
#pragma unroll
    for (int s = 0; s < 4; ++s) {
        fh->u[s] = pair_h(u[2 * s], u[2 * s + 1]);
        fl->u[s] = pair_l(u[2 * s], u[2 * s + 1]);
    }
}

// ---------------------------------------------------------------------------
// Kernel 1: feat = tensor @ W + b, split to fp16 hi/lo planes [B][D][M]
// ---------------------------------------------------------------------------
__global__ void feat_split_kernel(const float* __restrict__ tensor,
                                  const float* __restrict__ W,
                                  const float* __restrict__ bias,
                                  _Float16* __restrict__ fh,
                                  _Float16* __restrict__ fl) {
    int t  = blockIdx.x * blockDim.x + threadIdx.x; // 0..B*D*M-1
    int m  = t & (MM - 1);
    int bd = t >> 5;
    const float* tp = tensor + bd * NN;
    float acc = bias[m];
#pragma unroll
    for (int n = 0; n < NN; ++n) acc += tp[n] * W[n * MM + m];
    _Float16 h = (_Float16)acc;
    fh[t] = h;
    fl[t] = (_Float16)(acc - (float)h);
}

// ---------------------------------------------------------------------------
// Kernel 2: pre-pack G into MFMA B-fragment order, split fp16 hi/lo.
// For (c,d,tile,lane,r): value = G[c][d][i=tile>>1][m=8*(lane>>4)+r][j=16*(tile&1)+(lane&15)]
// dst flat index = gid*8 + r  (gid decomposes exactly as (((c*16+d)*64+tile)*64+lane))
// ---------------------------------------------------------------------------
__global__ void prep_g_kernel(const float* __restrict__ G,
                              _Float16* __restrict__ gh,
                              _Float16* __restrict__ gl) {
    int gid  = blockIdx.x * 256 + threadIdx.x;  // 0..655359
    int l    = gid & 63;
    int tile = (gid >> 6) & 63;
    int d    = (gid >> 12) & 15;
    int c    = gid >> 16;
    int i    = tile >> 1;
    int jj   = 16 * (tile & 1) + (l & 15);
    int q    = l >> 4;
    size_t dst = (size_t)gid * 8;
    const float* src = G + ((((size_t)c * DD + d) * RR + i) * MM + 8 * q) * RR + jj;
#pragma unroll
    for (int r = 0; r < 8; ++r) {
        float x = src[(size_t)r * RR];  // m = 8q + r, stride RR floats
        _Float16 h = (_Float16)x;
        gh[dst + r] = h;
        gl[dst + r] = (_Float16)(x - (float)h);
    }
}

// ---------------------------------------------------------------------------
// Kernel 3: per (c, b-block of 8): build 8 cores per d via MFMA into LDS
// (packed hi|lo dwords, layout LDS[b][j*RSTR + i] = cores[b][i][j]), then each
// wave w chain-multiplies its b=w product via mfma_f32_16x16x32_f16 with
// 3-term split products. C/D->A layout transform via LDS round-trip that
// aliases the wave's own core region (safe: region b is only read by wave b
// in phase 2, and barriers separate it from the next phase 1).
// ---------------------------------------------------------------------------
__global__ __launch_bounds__(512, 4) void chain_kernel(
    const _Float16* __restrict__ feat_h, const _Float16* __restrict__ feat_l,
    const _Float16* __restrict__ g_h,    const _Float16* __restrict__ g_l,
    float* __restrict__ logits) // [B][C]
{
    __shared__ unsigned int core[BBLK * BREG];  // 36864 B

    const int bid  = blockIdx.x;       // 0..639
    const int c    = bid / 64;         // same-c blocks consecutive (L2/L3 locality)
    const int b0   = (bid % 64) * BBLK;
    const int t    = threadIdx.x;
    const int w    = t >> 6;           // wave 0..7, owns b = w
    const int lane = t & 63;
    const int q    = lane >> 4;        // 0..3
    const int j4   = lane & 15;

    const int bA = min(b0 + j4, BB - 1);  // phase-1 A row (rows 8..15 are dummies)

    v4f acc[2][2];
    U4 pah[2], pal[2];  // P as A-fragments (hi/lo), per mi

    for (int d = 0; d < DD; ++d) {
        __syncthreads();  // prev phase-2 round-trip done; core writable
        // ---------------- phase 1: build cores for this d ----------------
        {
            const size_t fo = (size_t)bA * (DD * MM) + d * MM + q * 8;
            v8h afh = *(const v8h*)(feat_h + fo);
            v8h afl = *(const v8h*)(feat_l + fo);
            const size_t gbase = (size_t)(c * DD + d) * (64 * 64 * 8);
#pragma unroll
            for (int tt = 0; tt < 8; ++tt) {
                const int tile = w * 8 + tt;
                const size_t go = gbase + ((size_t)tile * 64 + lane) * 8;
                v8h gfh = *(const v8h*)(g_h + go);
                v8h gfl = *(const v8h*)(g_l + go);
                v4f a = {0.f, 0.f, 0.f, 0.f};
                a = __builtin_amdgcn_mfma_f32_16x16x32_f16(afh, gfh, a, 0, 0, 0);
                a = __builtin_amdgcn_mfma_f32_16x16x32_f16(afh, gfl, a, 0, 0, 0);
                a = __builtin_amdgcn_mfma_f32_16x16x32_f16(afl, gfh, a, 0, 0, 0);
                if (q < 2) {  // D rows 0..7 are the valid b's
                    const int i_idx = tile >> 1;
                    const int jcol  = 16 * (tile & 1) + j4;
#pragma unroll
                    for (int reg = 0; reg < 4; ++reg) {
                        int brow = 4 * q + reg;  // 0..7
                        core[brow * BREG + jcol * RSTR + i_idx] = split_pack(a[reg]);
                    }
                }
            }
        }
        __syncthreads();  // cores ready
        // ---------------- phase 2: wave w advances chain for b = w -------
        unsigned int* reg0 = core + w * BREG;
        if (d == 0) {
            // P = core_0: load A-frags directly (P[a][k] at LDS[k*RSTR + a])
#pragma unroll
            for (int mi = 0; mi < 2; ++mi) {
                unsigned int u[8];
#pragma unroll
                for (int r = 0; r < 8; ++r) {
                    int k = 8 * q + r;
                    u[r] = reg0[k * RSTR + 16 * mi + j4];
                }
                unpack8(u, &pah[mi], &pal[mi]);
            }
        } else {
            // B-frags of core: C[k=i][n=j] -> LDS[(16ni+j4)*RSTR + 8q + r]
            U4 bh[2], bl[2];
#pragma unroll
            for (int ni = 0; ni < 2; ++ni) {
                const uint4* rp = (const uint4*)(reg0 + (16 * ni + j4) * RSTR + 8 * q);
                uint4 x0 = rp[0], x1 = rp[1];
                unsigned int u[8] = {x0.x, x0.y, x0.z, x0.w, x1.x, x1.y, x1.z, x1.w};
                unpack8(u, &bh[ni], &bl[ni]);
            }
#pragma unroll
            for (int mi = 0; mi < 2; ++mi)
#pragma unroll
                for (int ni = 0; ni < 2; ++ni) {
                    v4f a = {0.f, 0.f, 0.f, 0.f};
                    a = __builtin_amdgcn_mfma_f32_16x16x32_f16(pah[mi].h, bh[ni].h, a, 0, 0, 0);
                    a = __builtin_amdgcn_mfma_f32_16x16x32_f16(pah[mi].h, bl[ni].h, a, 0, 0, 0);
                    a = __builtin_amdgcn_mfma_f32_16x16x32_f16(pal[mi].h, bh[ni].h, a, 0, 0, 0);
                    acc[mi][ni] = a;
                }
            if (d < DD - 1) {
                // round-trip: split P_new, write to own region, read back as A-frags
#pragma unroll
                for (int mi = 0; mi < 2; ++mi)
#pragma unroll
                    for (int ni = 0; ni < 2; ++ni)
#pragma unroll
                        for (int reg = 0; reg < 4; ++reg) {
                            int ar  = 16 * mi + 4 * q + reg;
                            int col = 16 * ni + j4;
                            reg0[ar * RSTR + col] = split_pack(acc[mi][ni][reg]);
                        }
                __builtin_amdgcn_sched_barrier(0);  // keep reads after writes
#pragma unroll
                for (int mi = 0; mi < 2; ++mi) {
                    const uint4* rp = (const uint4*)(reg0 + (16 * mi + j4) * RSTR + 8 * q);
                    uint4 x0 = rp[0], x1 = rp[1];
                    unsigned int u[8] = {x0.x, x0.y, x0.z, x0.w, x1.x, x1.y, x1.z, x1.w};
                    unpack8(u, &pah[mi], &pal[mi]);
                }
            }
        }
    }

    // trace from final accumulators: diag tiles (0,0),(1,1); row==col when 4q+reg==j4
    float tr = 0.f;
    if (q == (j4 >> 2)) {
        int reg = j4 & 3;
        tr = acc[0][0][reg] + acc[1][1][reg];
    }
#pragma unroll
    for (int off = 32; off > 0; off >>= 1) tr += __shfl_down(tr, off);
    if (lane == 0) logits[(b0 + w) * CC + c] = tr;
}

// ---------------------------------------------------------------------------
// Kernel 4: log-softmax over c, one thread per b
// ---------------------------------------------------------------------------
__global__ void lsm_kernel(const float* __restrict__ logits,
                           float* __restrict__ out) {
    int b = blockIdx.x * blockDim.x + threadIdx.x;
    if (b >= BB) return;
    float x[CC];
    float mx = -1e30f;
#pragma unroll
    for (int c = 0; c < CC; ++c) { x[c] = logits[b * CC + c]; mx = fmaxf(mx, x[c]); }
    float s = 0.f;
#pragma unroll
    for (int c = 0; c < CC; ++c) s += expf(x[c] - mx);
    float ls = logf(s);
#pragma unroll
    for (int c = 0; c < CC; ++c) out[b * CC + c] = x[c] - mx - ls;
}

// ---------------------------------------------------------------------------
extern "C" void kernel_launch(void* const* d_in, const int* in_sizes, int n_in,
                              void* d_out, int out_size, void* d_ws, size_t ws_size,
                              hipStream_t stream) {
    const float* tensor = (const float*)d_in[0];
    const float* W      = (const float*)d_in[1];
    const float* bias   = (const float*)d_in[2];
    const float* G      = (const float*)d_in[3];
    float* out = (float*)d_out;

    const size_t FEAT = (size_t)BB * DD * MM;        // 262144
    const size_t GPK  = (size_t)CC * DD * 64 * 64 * 8; // 5242880
    _Float16* fh = (_Float16*)d_ws;
    _Float16* fl = fh + FEAT;
    _Float16* gh = fl + FEAT;
    _Float16* gl = gh + GPK;
    float* logits = (float*)(gl + GPK);              // byte offset 22020096 (16B-aligned)

    feat_split_kernel<<<(int)(FEAT / 256), 256, 0, stream>>>(tensor, W, bias, fh, fl);
    prep_g_kernel<<<(int)(GPK / 8 / 256), 256, 0, stream>>>(G, gh, gl);
    chain_kernel<<<CC * (BB / BBLK), 512, 0, stream>>>(fh, fl, gh, gl, logits);
    lsm_kernel<<<(BB + 255) / 256, 256, 0, stream>>>(logits, out);
}

// Round 5
// 194.614 us; speedup vs baseline: 3.8861x; 1.2132x over previous
//
#include <hip/hip_runtime.h>
#include <math.h>

#define BB 512
#define DD 16
#define NN 64
#define MM 32
#define RR 32
#define CC 10
#define BBLK 8           // b's per chain block (= waves per block)
#define SS 2             // chain segments (d 0..7 | d 8..15)
#define DSEG (DD / SS)
#define RSTR 36          // dword stride of a core/scratch row (16B-aligned rows)
#define BREG (RR * RSTR) // 1152 dwords per b region

typedef _Float16 v8h __attribute__((ext_vector_type(8)));
typedef float v4f __attribute__((ext_vector_type(4)));

union U4 { unsigned int u[4]; v8h h; };

// split fp32 -> (hi fp16, lo fp16) packed in one dword: hi in [31:16], lo in [15:0]
__device__ __forceinline__ unsigned int split_pack(float x) {
    _Float16 h = (_Float16)x;
    _Float16 l = (_Float16)(x - (float)h);
    unsigned int hb = (unsigned int)__builtin_bit_cast(unsigned short, h);
    unsigned int lb = (unsigned int)__builtin_bit_cast(unsigned short, l);
    return (hb << 16) | lb;
}

__device__ __forceinline__ float unpackf(unsigned int u) {
    _Float16 h = __builtin_bit_cast(_Float16, (unsigned short)(u >> 16));
    _Float16 l = __builtin_bit_cast(_Float16, (unsigned short)(u & 0xffffu));
    return (float)h + (float)l;
}

__device__ __forceinline__ unsigned int pair_h(unsigned int ue, unsigned int uo) {
    return __builtin_amdgcn_perm(uo, ue, 0x07060302u); // [uo.h | ue.h]
}
__device__ __forceinline__ unsigned int pair_l(unsigned int ue, unsigned int uo) {
    return __builtin_amdgcn_perm(uo, ue, 0x05040100u); // [uo.l | ue.l]
}

__device__ __forceinline__ void unpack8(const unsigned int* u, U4* fh, U4* fl) {
#pragma unroll
    for (int s = 0; s < 4; ++s) {
        fh->u[s] = pair_h(u[2 * s], u[2 * s + 1]);
        fl->u[s] = pair_l(u[2 * s], u[2 * s + 1]);
    }
}

// ---------------------------------------------------------------------------
// Kernel 1: feat = tensor @ W + b, split to fp16 hi/lo planes [B][D][M]
// ---------------------------------------------------------------------------
__global__ void feat_split_kernel(const float* __restrict__ tensor,
                                  const float* __restrict__ W,
                                  const float* __restrict__ bias,
                                  _Float16* __restrict__ fh,
                                  _Float16* __restrict__ fl) {
    int t  = blockIdx.x * blockDim.x + threadIdx.x; // 0..B*D*M-1
    int m  = t & (MM - 1);
    int bd = t >> 5;
    const float* tp = tensor + bd * NN;
    float acc = bias[m];
#pragma unroll
    for (int n = 0; n < NN; ++n) acc += tp[n] * W[n * MM + m];
    _Float16 h = (_Float16)acc;
    fh[t] = h;
    fl[t] = (_Float16)(acc - (float)h);
}

// ---------------------------------------------------------------------------
// Kernel 2: pre-pack G into MFMA B-fragment order, split fp16 hi/lo.
// value = G[c][d][i=tile>>1][m=8*(lane>>4)+r][j=16*(tile&1)+(lane&15)]
// ---------------------------------------------------------------------------
__global__ void prep_g_kernel(const float* __restrict__ G,
                              _Float16* __restrict__ gh,
                              _Float16* __restrict__ gl) {
    int gid  = blockIdx.x * 256 + threadIdx.x;  // 0..655359
    int l    = gid & 63;
    int tile = (gid >> 6) & 63;
    int d    = (gid >> 12) & 15;
    int c    = gid >> 16;
    int i    = tile >> 1;
    int jj   = 16 * (tile & 1) + (l & 15);
    int q    = l >> 4;
    size_t dst = (size_t)gid * 8;
    const float* src = G + ((((size_t)c * DD + d) * RR + i) * MM + 8 * q) * RR + jj;
#pragma unroll
    for (int r = 0; r < 8; ++r) {
        float x = src[(size_t)r * RR];  // m = 8q + r, stride RR floats
        _Float16 h = (_Float16)x;
        gh[dst + r] = h;
        gl[dst + r] = (_Float16)(x - (float)h);
    }
}

// ---------------------------------------------------------------------------
// Kernel 3: per (c, b-block of 8, segment s): build 8 cores per d via MFMA
// into LDS (packed hi|lo dwords, layout LDS[b][j*RSTR + i]), chain-multiply
// the segment's 8 cores per wave, write split-packed 32x32 product to ws.
// Grid = CC * 64 * SS = 1280 = exactly 5 blocks/CU (round-4 lesson: grid 640
// -> 29% occupancy + 3:2 block imbalance was a main limiter).
// Phase-1 stores register-buffered per j-half -> 8 ds_write_b128 per wave/d
// instead of 32 scalar ds_write_b32 (round-4 conflict source, 1.04e7 cycles).
// ---------------------------------------------------------------------------
__global__ __launch_bounds__(512, 4) void chain_kernel(
    const _Float16* __restrict__ feat_h, const _Float16* __restrict__ feat_l,
    const _Float16* __restrict__ g_h,    const _Float16* __restrict__ g_l,
    unsigned int* __restrict__ segP)     // [C][B][SS][32][32] packed dwords
{
    __shared__ unsigned int core[BBLK * BREG];  // 36864 B

    const int bid  = blockIdx.x;       // 0..1279
    const int c    = bid >> 7;         // 128 consecutive blocks share c (L2/L3)
    const int rr   = bid & 127;
    const int s    = rr & 1;
    const int b0   = (rr >> 1) * BBLK;
    const int d0   = s * DSEG;
    const int t    = threadIdx.x;
    const int w    = t >> 6;           // wave 0..7, owns b = b0 + w
    const int lane = t & 63;
    const int q    = lane >> 4;        // 0..3
    const int j4   = lane & 15;

    const int bA = min(b0 + j4, BB - 1);  // phase-1 A row (rows 8..15 dummies)

    v4f acc[2][2];
    U4 pah[2], pal[2];  // P as A-fragments (hi/lo), per mi

    for (int dd = 0; dd < DSEG; ++dd) {
        const int d = d0 + dd;
        __syncthreads();  // prev phase-2 done; core writable
        // ---------------- phase 1: build cores for this d ----------------
        {
            const size_t fo = (size_t)bA * (DD * MM) + d * MM + q * 8;
            v8h afh = *(const v8h*)(feat_h + fo);
            v8h afl = *(const v8h*)(feat_l + fo);
            const size_t gbase = (size_t)(c * DD + d) * (64 * 64 * 8);
#pragma unroll
            for (int jh = 0; jh < 2; ++jh) {
                float av[4][4];
#pragma unroll
                for (int ii = 0; ii < 4; ++ii) {
                    const int tile = w * 8 + 2 * ii + jh;   // i = w*4+ii
                    const size_t go = gbase + ((size_t)tile * 64 + lane) * 8;
                    v8h gfh = *(const v8h*)(g_h + go);
                    v8h gfl = *(const v8h*)(g_l + go);
                    v4f a = {0.f, 0.f, 0.f, 0.f};
                    a = __builtin_amdgcn_mfma_f32_16x16x32_f16(afh, gfh, a, 0, 0, 0);
                    a = __builtin_amdgcn_mfma_f32_16x16x32_f16(afh, gfl, a, 0, 0, 0);
                    a = __builtin_amdgcn_mfma_f32_16x16x32_f16(afl, gfh, a, 0, 0, 0);
#pragma unroll
                    for (int reg = 0; reg < 4; ++reg) av[ii][reg] = a[reg];
                }
                if (q < 2) {  // D rows 0..7 are the valid b's
#pragma unroll
                    for (int reg = 0; reg < 4; ++reg) {
                        uint4 U;
                        U.x = split_pack(av[0][reg]);
                        U.y = split_pack(av[1][reg]);
                        U.z = split_pack(av[2][reg]);
                        U.w = split_pack(av[3][reg]);
                        *reinterpret_cast<uint4*>(
                            &core[(4 * q + reg) * BREG + (16 * jh + j4) * RSTR
                                  + 4 * w]) = U;
                    }
                }
            }
        }
        __syncthreads();  // cores ready
        // ---------------- phase 2: wave w advances chain for b = b0+w ----
        unsigned int* reg0 = core + w * BREG;
        if (dd == 0) {
            // P = core_d0: load A-frags directly (P[a][k] at LDS[k*RSTR + a])
#pragma unroll
            for (int mi = 0; mi < 2; ++mi) {
                unsigned int u[8];
#pragma unroll
                for (int r = 0; r < 8; ++r) {
                    int k = 8 * q + r;
                    u[r] = reg0[k * RSTR + 16 * mi + j4];
                }
                unpack8(u, &pah[mi], &pal[mi]);
            }
        } else {
            // B-frags of core: B[k][n] at LDS[n*RSTR + k], k-contiguous b128
            U4 bh[2], bl[2];
#pragma unroll
            for (int ni = 0; ni < 2; ++ni) {
                const uint4* rp = (const uint4*)(reg0 + (16 * ni + j4) * RSTR + 8 * q);
                uint4 x0 = rp[0], x1 = rp[1];
                unsigned int u[8] = {x0.x, x0.y, x0.z, x0.w, x1.x, x1.y, x1.z, x1.w};
                unpack8(u, &bh[ni], &bl[ni]);
            }
#pragma unroll
            for (int mi = 0; mi < 2; ++mi)
#pragma unroll
                for (int ni = 0; ni < 2; ++ni) {
                    v4f a = {0.f, 0.f, 0.f, 0.f};
                    a = __builtin_amdgcn_mfma_f32_16x16x32_f16(pah[mi].h, bh[ni].h, a, 0, 0, 0);
                    a = __builtin_amdgcn_mfma_f32_16x16x32_f16(pah[mi].h, bl[ni].h, a, 0, 0, 0);
                    a = __builtin_amdgcn_mfma_f32_16x16x32_f16(pal[mi].h, bh[ni].h, a, 0, 0, 0);
                    acc[mi][ni] = a;
                }
            if (dd < DSEG - 1) {
                // round-trip: split P_new, write to own region, read as A-frags
#pragma unroll
                for (int mi = 0; mi < 2; ++mi)
#pragma unroll
                    for (int ni = 0; ni < 2; ++ni)
#pragma unroll
                        for (int reg = 0; reg < 4; ++reg) {
                            int ar  = 16 * mi + 4 * q + reg;
                            int col = 16 * ni + j4;
                            reg0[ar * RSTR + col] = split_pack(acc[mi][ni][reg]);
                        }
                __builtin_amdgcn_sched_barrier(0);  // keep reads after writes
#pragma unroll
                for (int mi = 0; mi < 2; ++mi) {
                    const uint4* rp = (const uint4*)(reg0 + (16 * mi + j4) * RSTR + 8 * q);
                    uint4 x0 = rp[0], x1 = rp[1];
                    unsigned int u[8] = {x0.x, x0.y, x0.z, x0.w, x1.x, x1.y, x1.z, x1.w};
                    unpack8(u, &pah[mi], &pal[mi]);
                }
            }
        }
    }

    // write split-packed segment product (row-major 32x32 dwords)
    {
        unsigned int* dst = segP +
            ((size_t)(c * BB + (b0 + w)) * SS + s) * 1024;
#pragma unroll
        for (int mi = 0; mi < 2; ++mi)
#pragma unroll
            for (int ni = 0; ni < 2; ++ni)
#pragma unroll
                for (int reg = 0; reg < 4; ++reg) {
                    int row = 16 * mi + 4 * q + reg;
                    int col = 16 * ni + j4;
                    dst[row * 32 + col] = split_pack(acc[mi][ni][reg]);
                }
    }
}

// ---------------------------------------------------------------------------
// Kernel 4: per b: logits[c] = trace(P0 @ P1) = sum_il P0[i][l]*P1[l][i],
// then log-softmax. One wave per b (4 waves / 256-thread block).
// ---------------------------------------------------------------------------
__global__ __launch_bounds__(256) void combine_lsm_kernel(
    const unsigned int* __restrict__ segP,   // [C][B][SS][32][32] packed
    float* __restrict__ out)                 // [B][C]
{
    const int t    = threadIdx.x;
    const int b    = blockIdx.x * 4 + (t >> 6);
    const int lane = t & 63;
    const int i    = lane & 31;
    const int hf   = lane >> 5;       // 0 or 1

    float tr[CC];
#pragma unroll
    for (int c = 0; c < CC; ++c) {
        const unsigned int* P0 = segP + ((size_t)(c * BB + b) * SS + 0) * 1024;
        const unsigned int* P1 = P0 + 1024;
        const uint4* r0 = (const uint4*)(P0 + i * 32 + hf * 16);
        float acc = 0.f;
#pragma unroll
        for (int v = 0; v < 4; ++v) {
            uint4 x = r0[v];
            unsigned int us[4] = {x.x, x.y, x.z, x.w};
#pragma unroll
            for (int e = 0; e < 4; ++e) {
                int l = hf * 16 + v * 4 + e;
                acc += unpackf(us[e]) * unpackf(P1[l * 32 + i]);
            }
        }
        tr[c] = acc;
    }
#pragma unroll
    for (int c = 0; c < CC; ++c) {
#pragma unroll
        for (int off = 32; off > 0; off >>= 1)
            tr[c] += __shfl_down(tr[c], off);
    }
    if (lane == 0) {
        float mx = -1e30f;
#pragma unroll
        for (int c = 0; c < CC; ++c) mx = fmaxf(mx, tr[c]);
        float ssum = 0.f;
#pragma unroll
        for (int c = 0; c < CC; ++c) ssum += expf(tr[c] - mx);
        float ls = logf(ssum);
#pragma unroll
        for (int c = 0; c < CC; ++c) out[b * CC + c] = tr[c] - mx - ls;
    }
}

// ---------------------------------------------------------------------------
extern "C" void kernel_launch(void* const* d_in, const int* in_sizes, int n_in,
                              void* d_out, int out_size, void* d_ws, size_t ws_size,
                              hipStream_t stream) {
    const float* tensor = (const float*)d_in[0];
    const float* W      = (const float*)d_in[1];
    const float* bias   = (const float*)d_in[2];
    const float* G      = (const float*)d_in[3];
    float* out = (float*)d_out;

    const size_t FEAT = (size_t)BB * DD * MM;          // 262144
    const size_t GPK  = (size_t)CC * DD * 64 * 64 * 8; // 5242880
    _Float16* fh = (_Float16*)d_ws;
    _Float16* fl = fh + FEAT;
    _Float16* gh = fl + FEAT;
    _Float16* gl = gh + GPK;
    unsigned int* segP = (unsigned int*)(gl + GPK);    // 10*512*2*1024 dwords (42 MB)

    feat_split_kernel<<<(int)(FEAT / 256), 256, 0, stream>>>(tensor, W, bias, fh, fl);
    prep_g_kernel<<<(int)(GPK / 8 / 256), 256, 0, stream>>>(G, gh, gl);
    chain_kernel<<<CC * (BB / BBLK) * SS, 512, 0, stream>>>(fh, fl, gh, gl, segP);
    combine_lsm_kernel<<<BB / 4, 256, 0, stream>>>(segP, out);
}

// Round 6
// 169.794 us; speedup vs baseline: 4.4541x; 1.1462x over previous
//
#include <hip/hip_runtime.h>
#include <math.h>

#define BB 512
#define DD 16
#define NN 64
#define MM 32
#define RR 32
#define CC 10
#define BBLK 8           // b's per chain block (= waves per block)
#define SS 2             // chain segments (d 0..7 | d 8..15)
#define DSEG (DD / SS)
#define RSTR 36          // dword stride of a core/scratch row (16B-aligned rows)
#define BREG (RR * RSTR) // 1152 dwords per b region

typedef _Float16 v8h __attribute__((ext_vector_type(8)));
typedef float v4f __attribute__((ext_vector_type(4)));

union U4 { unsigned int u[4]; v8h h; };

// split fp32 -> (hi fp16, lo fp16) packed in one dword: hi in [31:16], lo in [15:0]
__device__ __forceinline__ unsigned int split_pack(float x) {
    _Float16 h = (_Float16)x;
    _Float16 l = (_Float16)(x - (float)h);
    unsigned int hb = (unsigned int)__builtin_bit_cast(unsigned short, h);
    unsigned int lb = (unsigned int)__builtin_bit_cast(unsigned short, l);
    return (hb << 16) | lb;
}

__device__ __forceinline__ float unpackf(unsigned int u) {
    _Float16 h = __builtin_bit_cast(_Float16, (unsigned short)(u >> 16));
    _Float16 l = __builtin_bit_cast(_Float16, (unsigned short)(u & 0xffffu));
    return (float)h + (float)l;
}

__device__ __forceinline__ unsigned int pair_h(unsigned int ue, unsigned int uo) {
    return __builtin_amdgcn_perm(uo, ue, 0x07060302u); // [uo.h | ue.h]
}
__device__ __forceinline__ unsigned int pair_l(unsigned int ue, unsigned int uo) {
    return __builtin_amdgcn_perm(uo, ue, 0x05040100u); // [uo.l | ue.l]
}

// hi-plane-only unpack (A operands are hi-fp16 only this round)
__device__ __forceinline__ void unpack_h(const unsigned int* u, U4* fh) {
#pragma unroll
    for (int s = 0; s < 4; ++s) fh->u[s] = pair_h(u[2 * s], u[2 * s + 1]);
}

__device__ __forceinline__ void unpack_hl(const unsigned int* u, U4* fh, U4* fl) {
#pragma unroll
    for (int s = 0; s < 4; ++s) {
        fh->u[s] = pair_h(u[2 * s], u[2 * s + 1]);
        fl->u[s] = pair_l(u[2 * s], u[2 * s + 1]);
    }
}

// ---------------------------------------------------------------------------
// Kernel 1 (merged producers):
//  blocks [0, 1024):    feat_h = fp16( tensor @ W + b )          [B][D][M]
//  blocks [1024, 3584): G pre-packed to MFMA B-frag order, split hi/lo
//    value = G[c][d][i=tile>>1][m=8*(lane>>4)+r][j=16*(tile&1)+(lane&15)]
// ---------------------------------------------------------------------------
__global__ void produce_kernel(const float* __restrict__ tensor,
                               const float* __restrict__ W,
                               const float* __restrict__ bias,
                               const float* __restrict__ G,
                               _Float16* __restrict__ fh,
                               _Float16* __restrict__ gh,
                               _Float16* __restrict__ gl) {
    if (blockIdx.x < 1024) {
        int t  = blockIdx.x * 256 + threadIdx.x; // 0..B*D*M-1
        int m  = t & (MM - 1);
        int bd = t >> 5;
        const float* tp = tensor + bd * NN;
        float acc = bias[m];
#pragma unroll
        for (int n = 0; n < NN; ++n) acc += tp[n] * W[n * MM + m];
        fh[t] = (_Float16)acc;
    } else {
        int gid  = (blockIdx.x - 1024) * 256 + threadIdx.x;  // 0..655359
        int l    = gid & 63;
        int tile = (gid >> 6) & 63;
        int d    = (gid >> 12) & 15;
        int c    = gid >> 16;
        int i    = tile >> 1;
        int jj   = 16 * (tile & 1) + (l & 15);
        int q    = l >> 4;
        size_t dst = (size_t)gid * 8;
        const float* src = G + ((((size_t)c * DD + d) * RR + i) * MM + 8 * q) * RR + jj;
#pragma unroll
        for (int r = 0; r < 8; ++r) {
            float x = src[(size_t)r * RR];  // m = 8q + r, stride RR floats
            _Float16 h = (_Float16)x;
            gh[dst + r] = h;
            gl[dst + r] = (_Float16)(x - (float)h);
        }
    }
}

// ---------------------------------------------------------------------------
// Kernel 2: per (c, b-block of 8, segment s): build 8 cores per d via MFMA
// into LDS (packed hi|lo dwords, layout LDS[b][j*RSTR + i]), chain-multiply
// the segment's 8 cores per wave, write split-packed 32x32 product to ws.
// Round-6 changes: A operands hi-only (2 MFMA/term-pair instead of 3 —
// B keeps the hi/lo split so products are fp16(A) x fp32ish(B));
// per-jh G-load hoisting (8 outstanding loads) + launch_bounds(512,3)
// (<=85 VGPR) to let the compiler keep them in flight.
// ---------------------------------------------------------------------------
__global__ __launch_bounds__(512, 3) void chain_kernel(
    const _Float16* __restrict__ feat_h,
    const _Float16* __restrict__ g_h, const _Float16* __restrict__ g_l,
    unsigned int* __restrict__ segP)  // [C][B][SS][32][32] packed dwords
{
    __shared__ unsigned int core[BBLK * BREG];  // 36864 B

    const int bid  = blockIdx.x;       // 0..1279
    const int c    = bid >> 7;         // 128 consecutive blocks share c (L2/L3)
    const int rr   = bid & 127;
    const int s    = rr & 1;
    const int b0   = (rr >> 1) * BBLK;
    const int d0   = s * DSEG;
    const int t    = threadIdx.x;
    const int w    = t >> 6;           // wave 0..7, owns b = b0 + w
    const int lane = t & 63;
    const int q    = lane >> 4;        // 0..3
    const int j4   = lane & 15;

    const int bA = min(b0 + j4, BB - 1);  // phase-1 A row (rows 8..15 dummies)

    v4f acc[2][2];
    U4 pah[2];                         // P as A-fragments (hi plane), per mi

    for (int dd = 0; dd < DSEG; ++dd) {
        const int d = d0 + dd;
        __syncthreads();  // prev phase-2 done; core writable
        // ---------------- phase 1: build cores for this d ----------------
        {
            const size_t fo = (size_t)bA * (DD * MM) + d * MM + q * 8;
            v8h afh = *(const v8h*)(feat_h + fo);
            const size_t gbase = (size_t)(c * DD + d) * (64 * 64 * 8);
#pragma unroll
            for (int jh = 0; jh < 2; ++jh) {
                // hoist this jh-group's 8 G loads ahead of the MFMAs
                v8h gfh[4], gfl[4];
#pragma unroll
                for (int ii = 0; ii < 4; ++ii) {
                    const int tile = w * 8 + 2 * ii + jh;   // i = w*4+ii
                    const size_t go = gbase + ((size_t)tile * 64 + lane) * 8;
                    gfh[ii] = *(const v8h*)(g_h + go);
                    gfl[ii] = *(const v8h*)(g_l + go);
                }
                float av[4][4];
#pragma unroll
                for (int ii = 0; ii < 4; ++ii) {
                    v4f a = {0.f, 0.f, 0.f, 0.f};
                    a = __builtin_amdgcn_mfma_f32_16x16x32_f16(afh, gfh[ii], a, 0, 0, 0);
                    a = __builtin_amdgcn_mfma_f32_16x16x32_f16(afh, gfl[ii], a, 0, 0, 0);
#pragma unroll
                    for (int reg = 0; reg < 4; ++reg) av[ii][reg] = a[reg];
                }
                if (q < 2) {  // D rows 0..7 are the valid b's
#pragma unroll
                    for (int reg = 0; reg < 4; ++reg) {
                        uint4 U;
                        U.x = split_pack(av[0][reg]);
                        U.y = split_pack(av[1][reg]);
                        U.z = split_pack(av[2][reg]);
                        U.w = split_pack(av[3][reg]);
                        *reinterpret_cast<uint4*>(
                            &core[(4 * q + reg) * BREG + (16 * jh + j4) * RSTR
                                  + 4 * w]) = U;
                    }
                }
            }
        }
        __syncthreads();  // cores ready
        // ---------------- phase 2: wave w advances chain for b = b0+w ----
        unsigned int* reg0 = core + w * BREG;
        if (dd == 0) {
            // P = core_d0: load A-frags directly (P[a][k] at LDS[k*RSTR + a])
#pragma unroll
            for (int mi = 0; mi < 2; ++mi) {
                unsigned int u[8];
#pragma unroll
                for (int r = 0; r < 8; ++r) {
                    int k = 8 * q + r;
                    u[r] = reg0[k * RSTR + 16 * mi + j4];
                }
                unpack_h(u, &pah[mi]);
            }
        } else {
            // B-frags of core: B[k][n] at LDS[n*RSTR + k], k-contiguous b128
            U4 bh[2], bl[2];
#pragma unroll
            for (int ni = 0; ni < 2; ++ni) {
                const uint4* rp = (const uint4*)(reg0 + (16 * ni + j4) * RSTR + 8 * q);
                uint4 x0 = rp[0], x1 = rp[1];
                unsigned int u[8] = {x0.x, x0.y, x0.z, x0.w, x1.x, x1.y, x1.z, x1.w};
                unpack_hl(u, &bh[ni], &bl[ni]);
            }
#pragma unroll
            for (int mi = 0; mi < 2; ++mi)
#pragma unroll
                for (int ni = 0; ni < 2; ++ni) {
                    v4f a = {0.f, 0.f, 0.f, 0.f};
                    a = __builtin_amdgcn_mfma_f32_16x16x32_f16(pah[mi].h, bh[ni].h, a, 0, 0, 0);
                    a = __builtin_amdgcn_mfma_f32_16x16x32_f16(pah[mi].h, bl[ni].h, a, 0, 0, 0);
                    acc[mi][ni] = a;
                }
            if (dd < DSEG - 1) {
                // round-trip: split P_new, write to own region, read as A-frags
#pragma unroll
                for (int mi = 0; mi < 2; ++mi)
#pragma unroll
                    for (int ni = 0; ni < 2; ++ni)
#pragma unroll
                        for (int reg = 0; reg < 4; ++reg) {
                            int ar  = 16 * mi + 4 * q + reg;
                            int col = 16 * ni + j4;
                            reg0[ar * RSTR + col] = split_pack(acc[mi][ni][reg]);
                        }
                __builtin_amdgcn_sched_barrier(0);  // keep reads after writes
#pragma unroll
                for (int mi = 0; mi < 2; ++mi) {
                    const uint4* rp = (const uint4*)(reg0 + (16 * mi + j4) * RSTR + 8 * q);
                    uint4 x0 = rp[0], x1 = rp[1];
                    unsigned int u[8] = {x0.x, x0.y, x0.z, x0.w, x1.x, x1.y, x1.z, x1.w};
                    unpack_h(u, &pah[mi]);
                }
            }
        }
    }

    // write split-packed segment product (row-major 32x32 dwords)
    {
        unsigned int* dst = segP +
            ((size_t)(c * BB + (b0 + w)) * SS + s) * 1024;
#pragma unroll
        for (int mi = 0; mi < 2; ++mi)
#pragma unroll
            for (int ni = 0; ni < 2; ++ni)
#pragma unroll
                for (int reg = 0; reg < 4; ++reg) {
                    int row = 16 * mi + 4 * q + reg;
                    int col = 16 * ni + j4;
                    dst[row * 32 + col] = split_pack(acc[mi][ni][reg]);
                }
    }
}

// ---------------------------------------------------------------------------
// Kernel 3: per b: logits[c] = trace(P0 @ P1) = sum_il P0[i][l]*P1[l][i],
// then log-softmax. One wave per b (4 waves / 256-thread block).
// ---------------------------------------------------------------------------
__global__ __launch_bounds__(256) void combine_lsm_kernel(
    const unsigned int* __restrict__ segP,   // [C][B][SS][32][32] packed
    float* __restrict__ out)                 // [B][C]
{
    const int t    = threadIdx.x;
    const int b    = blockIdx.x * 4 + (t >> 6);
    const int lane = t & 63;
    const int i    = lane & 31;
    const int hf   = lane >> 5;       // 0 or 1

    float tr[CC];
#pragma unroll
    for (int c = 0; c < CC; ++c) {
        const unsigned int* P0 = segP + ((size_t)(c * BB + b) * SS + 0) * 1024;
        const unsigned int* P1 = P0 + 1024;
        const uint4* r0 = (const uint4*)(P0 + i * 32 + hf * 16);
        float acc = 0.f;
#pragma unroll
        for (int v = 0; v < 4; ++v) {
            uint4 x = r0[v];
            unsigned int us[4] = {x.x, x.y, x.z, x.w};
#pragma unroll
            for (int e = 0; e < 4; ++e) {
                int l = hf * 16 + v * 4 + e;
                acc += unpackf(us[e]) * unpackf(P1[l * 32 + i]);
            }
        }
        tr[c] = acc;
    }
#pragma unroll
    for (int c = 0; c < CC; ++c) {
#pragma unroll
        for (int off = 32; off > 0; off >>= 1)
            tr[c] += __shfl_down(tr[c], off);
    }
    if (lane == 0) {
        float mx = -1e30f;
#pragma unroll
        for (int c = 0; c < CC; ++c) mx = fmaxf(mx, tr[c]);
        float ssum = 0.f;
#pragma unroll
        for (int c = 0; c < CC; ++c) ssum += expf(tr[c] - mx);
        float ls = logf(ssum);
#pragma unroll
        for (int c = 0; c < CC; ++c) out[b * CC + c] = tr[c] - mx - ls;
    }
}

// ---------------------------------------------------------------------------
extern "C" void kernel_launch(void* const* d_in, const int* in_sizes, int n_in,
                              void* d_out, int out_size, void* d_ws, size_t ws_size,
                              hipStream_t stream) {
    const float* tensor = (const float*)d_in[0];
    const float* W      = (const float*)d_in[1];
    const float* bias   = (const float*)d_in[2];
    const float* G      = (const float*)d_in[3];
    float* out = (float*)d_out;

    const size_t FEAT = (size_t)BB * DD * MM;          // 262144
    const size_t GPK  = (size_t)CC * DD * 64 * 64 * 8; // 5242880
    _Float16* fh = (_Float16*)d_ws;
    _Float16* gh = fh + FEAT;
    _Float16* gl = gh + GPK;
    unsigned int* segP = (unsigned int*)(gl + GPK);    // 10*512*2*1024 dwords (42 MB)

    produce_kernel<<<1024 + (int)(GPK / 8 / 256), 256, 0, stream>>>(
        tensor, W, bias, G, fh, gh, gl);
    chain_kernel<<<CC * (BB / BBLK) * SS, 512, 0, stream>>>(fh, gh, gl, segP);
    combine_lsm_kernel<<<BB / 4, 256, 0, stream>>>(segP, out);
}

// Round 7
// 135.138 us; speedup vs baseline: 5.5963x; 1.2564x over previous
//
#include <hip/hip_runtime.h>
#include <math.h>

#define BB 512
#define DD 16
#define NN 64
#define MM 32
#define RR 32
#define CC 10
#define BBLK 16          // b's per chain block (8 waves, 2 chains/wave)
#define SS 2             // chain segments (d 0..7 | d 8..15)
#define DSEG (DD / SS)
#define ROWH 40          // halves per LDS row (80 B, 16B-aligned)
#define BREGH 1304       // halves per b region (652 dw = 2608 B; mod-32=12 dw for bank spread)

typedef _Float16 v8h __attribute__((ext_vector_type(8)));
typedef float v4f __attribute__((ext_vector_type(4)));

union H8 { unsigned int u[4]; v8h h; _Float16 e[8]; };
union H4 { unsigned int u[2]; _Float16 e[4]; };

// split fp32 -> (hi fp16 [31:16], lo fp16 [15:0]) — used only for segP output
__device__ __forceinline__ unsigned int split_pack(float x) {
    _Float16 h = (_Float16)x;
    _Float16 l = (_Float16)(x - (float)h);
    unsigned int hb = (unsigned int)__builtin_bit_cast(unsigned short, h);
    unsigned int lb = (unsigned int)__builtin_bit_cast(unsigned short, l);
    return (hb << 16) | lb;
}

__device__ __forceinline__ float unpackf(unsigned int u) {
    _Float16 h = __builtin_bit_cast(_Float16, (unsigned short)(u >> 16));
    _Float16 l = __builtin_bit_cast(_Float16, (unsigned short)(u & 0xffffu));
    return (float)h + (float)l;
}

// ---------------------------------------------------------------------------
// Kernel 1 (merged producers):
//  blocks [0,1024):    feat_h = fp16( tensor @ W + b )              [B][D][M]
//  blocks [1024,3584): G packed to MFMA B-frag order, fp16 hi only.
//    value = G[c][d][i=tile>>1][m=8*(lane>>4)+r][j=16*(tile&1)+(lane&15)]
//    (vectorized 16B store — round-6's 16 scalar 2B stores were the
//     suspected bulk of the ~80 µs non-chain gap)
// ---------------------------------------------------------------------------
__global__ void produce_kernel(const float* __restrict__ tensor,
                               const float* __restrict__ W,
                               const float* __restrict__ bias,
                               const float* __restrict__ G,
                               _Float16* __restrict__ fh,
                               _Float16* __restrict__ gh) {
    if (blockIdx.x < 1024) {
        int t  = blockIdx.x * 256 + threadIdx.x; // 0..B*D*M-1
        int m  = t & (MM - 1);
        int bd = t >> 5;
        const float* tp = tensor + bd * NN;
        float acc = bias[m];
#pragma unroll
        for (int n = 0; n < NN; ++n) acc += tp[n] * W[n * MM + m];
        fh[t] = (_Float16)acc;
    } else {
        int gid  = (blockIdx.x - 1024) * 256 + threadIdx.x;  // 0..655359
        int l    = gid & 63;
        int tile = (gid >> 6) & 63;
        int d    = (gid >> 12) & 15;
        int c    = gid >> 16;
        int i    = tile >> 1;
        int jj   = 16 * (tile & 1) + (l & 15);
        int q    = l >> 4;
        const float* src = G + ((((size_t)c * DD + d) * RR + i) * MM + 8 * q) * RR + jj;
        H8 v;
#pragma unroll
        for (int r = 0; r < 8; ++r)
            v.e[r] = (_Float16)src[(size_t)r * RR];   // m = 8q + r
        *(v8h*)(gh + (size_t)gid * 8) = v.h;
    }
}

// ---------------------------------------------------------------------------
// Kernel 2: per (c, b-block of 16, segment s): build 16 cores per d via MFMA
// (single-plane fp16, direct b64 stores — no hi|lo packing), each of the 8
// waves chain-multiplies 2 b's. LDS layouts within a b region (stride ROWH):
//   cores (p1 out / p2 B): L[j][k] = core[k][j]  (k contiguous -> b128 B-frag)
//   P round-trip (p2 out / next A): L[row][col]  (col contiguous -> b128 A-frag)
// Grid 640, all co-resident at 3 blocks/CU (launch_bounds(512,6), 40.7 KB LDS).
// ---------------------------------------------------------------------------
__global__ __launch_bounds__(512, 6) void chain_kernel(
    const _Float16* __restrict__ feat_h,
    const _Float16* __restrict__ g_h,
    unsigned int* __restrict__ segP)  // [C][B][SS][32][32] split-packed dwords
{
    __shared__ __align__(16) _Float16 lds[BBLK * BREGH];  // 41728 B

    const int bid  = blockIdx.x;       // 0..639
    const int c    = bid >> 6;         // 64 consecutive blocks share c (L2 reuse)
    const int rem  = bid & 63;
    const int s    = rem & 1;
    const int b0   = (rem >> 1) * BBLK;
    const int d0   = s * DSEG;
    const int t    = threadIdx.x;
    const int w    = t >> 6;           // wave 0..7
    const int lane = t & 63;
    const int q    = lane >> 4;        // 0..3
    const int j4   = lane & 15;

    v8h pah[2][2];                     // [chain cc][mi] A-fragments of P

    for (int dd = 0; dd < DSEG; ++dd) {
        const int d = d0 + dd;
        __syncthreads();   // all p2 reads of previous d done; lds writable
        // ---------------- phase 1: build 16 cores for this d -------------
        {
            const size_t fo = (size_t)(b0 + j4) * (DD * MM) + d * MM + q * 8;
            v8h afh = *(const v8h*)(feat_h + fo);     // A[b=j4][m=8q+r], all valid
            const size_t gbase = (size_t)(c * DD + d) * 32768;
#pragma unroll
            for (int jh = 0; jh < 2; ++jh) {
                v4f av[4];
#pragma unroll
                for (int ii = 0; ii < 4; ++ii) {
                    const int tile = w * 8 + 2 * ii + jh;   // core row k = 4w+ii
                    v8h g = *(const v8h*)(g_h + gbase + ((size_t)tile * 64 + lane) * 8);
                    v4f z = {0.f, 0.f, 0.f, 0.f};
                    av[ii] = __builtin_amdgcn_mfma_f32_16x16x32_f16(afh, g, z, 0, 0, 0);
                }
                // D[row=4q+reg -> b][col=j4 -> j], k=4w+ii contiguous in LDS
#pragma unroll
                for (int reg = 0; reg < 4; ++reg) {
                    H4 hv;
                    hv.e[0] = (_Float16)av[0][reg];
                    hv.e[1] = (_Float16)av[1][reg];
                    hv.e[2] = (_Float16)av[2][reg];
                    hv.e[3] = (_Float16)av[3][reg];
                    *reinterpret_cast<uint2*>(
                        &lds[(4 * q + reg) * BREGH + (16 * jh + j4) * ROWH + 4 * w]) =
                        make_uint2(hv.u[0], hv.u[1]);
                }
            }
        }
        __syncthreads();   // cores ready
        // ---------------- phase 2: wave w advances chains b=2w, 2w+1 -----
#pragma unroll
        for (int cc = 0; cc < 2; ++cc) {
            const int b = 2 * w + cc;
            _Float16* base = lds + b * BREGH;
            if (dd == 0) {
                // P = core_d0: A[m=16mi+j4][k'=8q+r] = core[m][k'] = L[k'][m]
#pragma unroll
                for (int mi = 0; mi < 2; ++mi) {
                    H8 a;
#pragma unroll
                    for (int r = 0; r < 8; ++r)
                        a.e[r] = base[(8 * q + r) * ROWH + 16 * mi + j4];
                    pah[cc][mi] = a.h;
                }
            } else {
                v8h bf[2];
#pragma unroll
                for (int ni = 0; ni < 2; ++ni)
                    bf[ni] = *(const v8h*)(base + (16 * ni + j4) * ROWH + 8 * q);
                v4f acc[2][2];
#pragma unroll
                for (int mi = 0; mi < 2; ++mi)
#pragma unroll
                    for (int ni = 0; ni < 2; ++ni) {
                        v4f z = {0.f, 0.f, 0.f, 0.f};
                        acc[mi][ni] = __builtin_amdgcn_mfma_f32_16x16x32_f16(
                            pah[cc][mi], bf[ni], z, 0, 0, 0);
                    }
                if (dd < DSEG - 1) {
                    // round-trip: store P_new [row][col], read back A-frags
#pragma unroll
                    for (int mi = 0; mi < 2; ++mi)
#pragma unroll
                        for (int ni = 0; ni < 2; ++ni)
#pragma unroll
                            for (int reg = 0; reg < 4; ++reg)
                                base[(16 * mi + 4 * q + reg) * ROWH + 16 * ni + j4] =
                                    (_Float16)acc[mi][ni][reg];
                    __builtin_amdgcn_sched_barrier(0);  // reads after writes
#pragma unroll
                    for (int mi = 0; mi < 2; ++mi)
                        pah[cc][mi] = *(const v8h*)(base + (16 * mi + j4) * ROWH + 8 * q);
                } else {
                    // final: write split-packed segment product
                    unsigned int* dst = segP +
                        ((size_t)(c * BB + (b0 + b)) * SS + s) * 1024;
#pragma unroll
                    for (int mi = 0; mi < 2; ++mi)
#pragma unroll
                        for (int ni = 0; ni < 2; ++ni)
#pragma unroll
                            for (int reg = 0; reg < 4; ++reg)
                                dst[(16 * mi + 4 * q + reg) * 32 + 16 * ni + j4] =
                                    split_pack(acc[mi][ni][reg]);
                }
            }
        }
    }
}

// ---------------------------------------------------------------------------
// Kernel 3: per b: logits[c] = trace(P0 @ P1) = sum_il P0[i][l]*P1[l][i],
// then log-softmax. One wave per b (4 waves / 256-thread block).
// ---------------------------------------------------------------------------
__global__ __launch_bounds__(256) void combine_lsm_kernel(
    const unsigned int* __restrict__ segP,   // [C][B][SS][32][32] packed
    float* __restrict__ out)                 // [B][C]
{
    const int t    = threadIdx.x;
    const int b    = blockIdx.x * 4 + (t >> 6);
    const int lane = t & 63;
    const int i    = lane & 31;
    const int hf   = lane >> 5;       // 0 or 1

    float tr[CC];
#pragma unroll
    for (int c = 0; c < CC; ++c) {
        const unsigned int* P0 = segP + ((size_t)(c * BB + b) * SS + 0) * 1024;
        const unsigned int* P1 = P0 + 1024;
        const uint4* r0 = (const uint4*)(P0 + i * 32 + hf * 16);
        float acc = 0.f;
#pragma unroll
        for (int v = 0; v < 4; ++v) {
            uint4 x = r0[v];
            unsigned int us[4] = {x.x, x.y, x.z, x.w};
#pragma unroll
            for (int e = 0; e < 4; ++e) {
                int l = hf * 16 + v * 4 + e;
                acc += unpackf(us[e]) * unpackf(P1[l * 32 + i]);
            }
        }
        tr[c] = acc;
    }
#pragma unroll
    for (int c = 0; c < CC; ++c) {
#pragma unroll
        for (int off = 32; off > 0; off >>= 1)
            tr[c] += __shfl_down(tr[c], off);
    }
    if (lane == 0) {
        float mx = -1e30f;
#pragma unroll
        for (int c = 0; c < CC; ++c) mx = fmaxf(mx, tr[c]);
        float ssum = 0.f;
#pragma unroll
        for (int c = 0; c < CC; ++c) ssum += expf(tr[c] - mx);
        float ls = logf(ssum);
#pragma unroll
        for (int c = 0; c < CC; ++c) out[b * CC + c] = tr[c] - mx - ls;
    }
}

// ---------------------------------------------------------------------------
extern "C" void kernel_launch(void* const* d_in, const int* in_sizes, int n_in,
                              void* d_out, int out_size, void* d_ws, size_t ws_size,
                              hipStream_t stream) {
    const float* tensor = (const float*)d_in[0];
    const float* W      = (const float*)d_in[1];
    const float* bias   = (const float*)d_in[2];
    const float* G      = (const float*)d_in[3];
    float* out = (float*)d_out;

    const size_t FEAT = (size_t)BB * DD * MM;          // 262144 halves
    const size_t GPK  = (size_t)CC * DD * 64 * 64 * 8; // 5242880 halves
    _Float16* fh = (_Float16*)d_ws;
    _Float16* gh = fh + FEAT;
    unsigned int* segP = (unsigned int*)(gh + GPK);    // byte off 11010048, 16B-aligned

    produce_kernel<<<1024 + (int)(GPK / 8 / 256), 256, 0, stream>>>(
        tensor, W, bias, G, fh, gh);
    chain_kernel<<<CC * (BB / BBLK) * SS, 512, 0, stream>>>(fh, gh, segP);
    combine_lsm_kernel<<<BB / 4, 256, 0, stream>>>(segP, out);
}

// Round 8
// 125.064 us; speedup vs baseline: 6.0471x; 1.0806x over previous
//
#include <hip/hip_runtime.h>
#include <math.h>

#define BB 512
#define DD 16
#define NN 64
#define MM 32
#define RR 32
#define CC 10
#define BBLK 8           // b's per chain block = waves per block (1 chain/wave)
#define ROWH 40          // halves per LDS row (80 B, 16B-aligned)
#define BREGH 1304       // halves per b region (652 dw; mod-32=12 for bank spread)

typedef _Float16 v8h __attribute__((ext_vector_type(8)));
typedef float v4f __attribute__((ext_vector_type(4)));

union H8 { unsigned int u[4]; v8h h; _Float16 e[8]; };
union H4 { unsigned int u[2]; _Float16 e[4]; };

// ---------------------------------------------------------------------------
// Kernel 1 (merged producers):
//  blocks [0,1024):    feat_h = fp16( tensor @ W + b )              [B][D][M]
//  blocks [1024,3584): G packed to MFMA B-frag order, fp16.
//    value = G[c][d][i=tile>>1][m=8*(lane>>4)+r][j=16*(tile&1)+(lane&15)]
// ---------------------------------------------------------------------------
__global__ void produce_kernel(const float* __restrict__ tensor,
                               const float* __restrict__ W,
                               const float* __restrict__ bias,
                               const float* __restrict__ G,
                               _Float16* __restrict__ fh,
                               _Float16* __restrict__ gh) {
    if (blockIdx.x < 1024) {
        int t  = blockIdx.x * 256 + threadIdx.x; // 0..B*D*M-1
        int m  = t & (MM - 1);
        int bd = t >> 5;
        const float* tp = tensor + bd * NN;
        float acc = bias[m];
#pragma unroll
        for (int n = 0; n < NN; ++n) acc += tp[n] * W[n * MM + m];
        fh[t] = (_Float16)acc;
    } else {
        int gid  = (blockIdx.x - 1024) * 256 + threadIdx.x;  // 0..655359
        int l    = gid & 63;
        int tile = (gid >> 6) & 63;
        int d    = (gid >> 12) & 15;
        int c    = gid >> 16;
        int i    = tile >> 1;
        int jj   = 16 * (tile & 1) + (l & 15);
        int q    = l >> 4;
        const float* src = G + ((((size_t)c * DD + d) * RR + i) * MM + 8 * q) * RR + jj;
        H8 v;
#pragma unroll
        for (int r = 0; r < 8; ++r)
            v.e[r] = (_Float16)src[(size_t)r * RR];   // m = 8q + r
        *(v8h*)(gh + (size_t)gid * 8) = v.h;
    }
}

// ---------------------------------------------------------------------------
// Kernel 2: per (c, b-block of 8): full 16-d chain in one block.
// Phase-1 builds the 8 cores (A rows 8..15 are dummy b's — MFMA waste is free
// at 7.5% MfmaUtil) with G-fragments PREFETCHED one d ahead in registers, so
// global-load latency overlaps p2 + both barriers. Phase-2: wave w chains
// b = b0+w (4 MFMA + fp16 LDS round-trip per d). Final trace from registers:
// no segment product, no segP traffic, no combine kernel (ws 53 -> 11 MB).
// ---------------------------------------------------------------------------
__global__ __launch_bounds__(512, 4) void chain_kernel(
    const _Float16* __restrict__ feat_h,
    const _Float16* __restrict__ g_h,
    float* __restrict__ logits)        // [B][C]
{
    __shared__ __align__(16) _Float16 lds[BBLK * BREGH];  // 20864 B

    const int bid  = blockIdx.x;       // 0..639
    const int c    = bid >> 6;         // 64 consecutive blocks share c (L2 reuse)
    const int b0   = (bid & 63) * BBLK;
    const int t    = threadIdx.x;
    const int w    = t >> 6;           // wave 0..7, chains b = b0 + w
    const int lane = t & 63;
    const int q    = lane >> 4;        // 0..3
    const int j4   = lane & 15;

    const size_t gbase_c = (size_t)c * DD * 32768;
    const int bA = b0 + (j4 & 7);      // A rows: j4 0..7 valid, 8..15 duplicates

    // ---- prefetch d = 0 fragments into registers ----
    v8h afh = *(const v8h*)(feat_h + (size_t)bA * (DD * MM) + 0 * MM + q * 8);
    v8h gf[8];
#pragma unroll
    for (int u = 0; u < 8; ++u) {      // u = 2*ii + jh; core row k = 4w + ii
        const int tile = w * 8 + u;
        gf[u] = *(const v8h*)(g_h + gbase_c + ((size_t)tile * 64 + lane) * 8);
    }

    v8h pah[2];
    v4f acc[2][2];

    for (int d = 0; d < DD; ++d) {
        __syncthreads();   // WAR: previous p2 reads of lds done
        // ---------------- phase 1: 8 MFMAs on prefetched fragments -------
        v4f av[8];
#pragma unroll
        for (int u = 0; u < 8; ++u) {
            v4f z = {0.f, 0.f, 0.f, 0.f};
            av[u] = __builtin_amdgcn_mfma_f32_16x16x32_f16(afh, gf[u], z, 0, 0, 0);
        }
        // ---- issue d+1 prefetch now: overlaps stores, p2, both barriers --
        if (d < DD - 1) {
            afh = *(const v8h*)(feat_h + (size_t)bA * (DD * MM) + (d + 1) * MM + q * 8);
            const size_t gb = gbase_c + (size_t)(d + 1) * 32768;
#pragma unroll
            for (int u = 0; u < 8; ++u) {
                const int tile = w * 8 + u;
                gf[u] = *(const v8h*)(g_h + gb + ((size_t)tile * 64 + lane) * 8);
            }
        }
        // store core rows for valid b's (row = 4q+reg < 8  ->  q < 2)
        if (q < 2) {
#pragma unroll
            for (int jh = 0; jh < 2; ++jh)
#pragma unroll
                for (int reg = 0; reg < 4; ++reg) {
                    H4 hv;
                    hv.e[0] = (_Float16)av[0 * 2 + jh][reg];   // k = 4w+0
                    hv.e[1] = (_Float16)av[1 * 2 + jh][reg];   // k = 4w+1
                    hv.e[2] = (_Float16)av[2 * 2 + jh][reg];
                    hv.e[3] = (_Float16)av[3 * 2 + jh][reg];
                    *reinterpret_cast<uint2*>(
                        &lds[(4 * q + reg) * BREGH + (16 * jh + j4) * ROWH + 4 * w]) =
                        make_uint2(hv.u[0], hv.u[1]);
                }
        }
        __syncthreads();   // RAW: cores ready
        // ---------------- phase 2: wave w advances its chain -------------
        _Float16* base = lds + w * BREGH;
        if (d == 0) {
            // P = core_0: A[m=16mi+j4][k=8q+r] = core[m][k] = L[k][m]
#pragma unroll
            for (int mi = 0; mi < 2; ++mi) {
                H8 a;
#pragma unroll
                for (int r = 0; r < 8; ++r)
                    a.e[r] = base[(8 * q + r) * ROWH + 16 * mi + j4];
                pah[mi] = a.h;
            }
        } else {
            v8h bf[2];
#pragma unroll
            for (int ni = 0; ni < 2; ++ni)
                bf[ni] = *(const v8h*)(base + (16 * ni + j4) * ROWH + 8 * q);
#pragma unroll
            for (int mi = 0; mi < 2; ++mi)
#pragma unroll
                for (int ni = 0; ni < 2; ++ni) {
                    v4f z = {0.f, 0.f, 0.f, 0.f};
                    acc[mi][ni] = __builtin_amdgcn_mfma_f32_16x16x32_f16(
                        pah[mi], bf[ni], z, 0, 0, 0);
                }
            if (d < DD - 1) {
                // round-trip: store P_new [row][col] fp16, read back A-frags
#pragma unroll
                for (int mi = 0; mi < 2; ++mi)
#pragma unroll
                    for (int ni = 0; ni < 2; ++ni)
#pragma unroll
                        for (int reg = 0; reg < 4; ++reg)
                            base[(16 * mi + 4 * q + reg) * ROWH + 16 * ni + j4] =
                                (_Float16)acc[mi][ni][reg];
                __builtin_amdgcn_sched_barrier(0);  // reads after writes
#pragma unroll
                for (int mi = 0; mi < 2; ++mi)
                    pah[mi] = *(const v8h*)(base + (16 * mi + j4) * ROWH + 8 * q);
            }
        }
    }

    // trace from final accumulators: row = 16mi+4q+reg, col = 16ni+j4;
    // diagonal (mi==ni) hit iff 4q+reg == j4
    float tr = 0.f;
    if (q == (j4 >> 2)) {
        int reg = j4 & 3;
        tr = acc[0][0][reg] + acc[1][1][reg];
    }
#pragma unroll
    for (int off = 32; off > 0; off >>= 1) tr += __shfl_down(tr, off);
    if (lane == 0) logits[(b0 + w) * CC + c] = tr;
}

// ---------------------------------------------------------------------------
// Kernel 3: log-softmax over c, one thread per b
// ---------------------------------------------------------------------------
__global__ void lsm_kernel(const float* __restrict__ logits,
                           float* __restrict__ out) {
    int b = blockIdx.x * blockDim.x + threadIdx.x;
    if (b >= BB) return;
    float x[CC];
    float mx = -1e30f;
#pragma unroll
    for (int c = 0; c < CC; ++c) { x[c] = logits[b * CC + c]; mx = fmaxf(mx, x[c]); }
    float s = 0.f;
#pragma unroll
    for (int c = 0; c < CC; ++c) s += expf(x[c] - mx);
    float ls = logf(s);
#pragma unroll
    for (int c = 0; c < CC; ++c) out[b * CC + c] = x[c] - mx - ls;
}

// ---------------------------------------------------------------------------
extern "C" void kernel_launch(void* const* d_in, const int* in_sizes, int n_in,
                              void* d_out, int out_size, void* d_ws, size_t ws_size,
                              hipStream_t stream) {
    const float* tensor = (const float*)d_in[0];
    const float* W      = (const float*)d_in[1];
    const float* bias   = (const float*)d_in[2];
    const float* G      = (const float*)d_in[3];
    float* out = (float*)d_out;

    const size_t FEAT = (size_t)BB * DD * MM;          // 262144 halves
    const size_t GPK  = (size_t)CC * DD * 64 * 64 * 8; // 5242880 halves
    _Float16* fh = (_Float16*)d_ws;
    _Float16* gh = fh + FEAT;
    float* logits = (float*)(gh + GPK);                // 5120 floats; ws ~11 MB

    produce_kernel<<<1024 + (int)(GPK / 8 / 256), 256, 0, stream>>>(
        tensor, W, bias, G, fh, gh);
    chain_kernel<<<CC * (BB / BBLK), 512, 0, stream>>>(fh, gh, logits);
    lsm_kernel<<<(BB + 255) / 256, 256, 0, stream>>>(logits, out);
}

// Round 9
// 120.837 us; speedup vs baseline: 6.2587x; 1.0350x over previous
//
#include <hip/hip_runtime.h>
#include <math.h>

#define BB 512
#define DD 16
#define NN 64
#define MM 32
#define RR 32
#define CC 10
#define BBLK 16          // b's per chain block (8 waves, 2 chains/wave)
#define SS 2             // chain segments (d 0..7 | d 8..15)
#define DSEG (DD / SS)
#define ROWH 40          // halves per LDS row (80 B, 16B-aligned)
#define BREGH 1304       // halves per b region

typedef _Float16 v8h __attribute__((ext_vector_type(8)));
typedef float v4f __attribute__((ext_vector_type(4)));

union H8 { unsigned int u[4]; v8h h; _Float16 e[8]; };
union H4 { unsigned int u[2]; _Float16 e[4]; };

// ---------------------------------------------------------------------------
// Kernel 1 (merged producers, all coalesced via LDS staging):
//  blocks [0,1024):      feat_h = fp16( tensor @ W + b )   [B][D][M]
//  blocks [1024,1344):   per (c,d,half-slab): G -> gh in MFMA B-frag order
//    gh[(((c*16+d)*64 + tile)*64 + lane)*8 + r] =
//        fp16( G[c][d][i=tile>>1][m=8*(lane>>4)+r][j=16*(tile&1)+(lane&15)] )
// ---------------------------------------------------------------------------
__global__ __launch_bounds__(256) void produce_kernel(
    const float* __restrict__ tensor, const float* __restrict__ W,
    const float* __restrict__ bias,   const float* __restrict__ G,
    _Float16* __restrict__ fh,        _Float16* __restrict__ gh) {
    __shared__ __align__(16) char smem[36864];
    const int t = threadIdx.x;
    if (blockIdx.x < 1024) {
        float* ten_s = (float*)smem;          // [8][64]
        float* W_s   = (float*)smem + 512;    // [64][32]
        const int bd0 = blockIdx.x * 8;
        if (t < 128)
            *(float4*)(ten_s + t * 4) = *(const float4*)(tensor + bd0 * NN + t * 4);
        *(float4*)(W_s + t * 4)        = *(const float4*)(W + t * 4);
        *(float4*)(W_s + 1024 + t * 4) = *(const float4*)(W + 1024 + t * 4);
        __syncthreads();
        const int m = t & 31, bd_l = t >> 5;
        float acc = bias[m];
#pragma unroll
        for (int n = 0; n < NN; ++n) acc += ten_s[bd_l * NN + n] * W_s[n * MM + m];
        fh[(bd0 + bd_l) * MM + m] = (_Float16)acc;
    } else {
        _Float16* lg = (_Float16*)smem;       // [di][m][j], m-stride 36 halves
        const int pb = blockIdx.x - 1024;     // 0..319
        const int c  = pb >> 5;
        const int d  = (pb >> 1) & 15;
        const int hf = pb & 1;
        const float* src = G + (size_t)(c * DD + d) * 32768 + hf * 16384;
#pragma unroll
        for (int k = 0; k < 16; ++k) {        // coalesced read of 64 KB slab-half
            const int f = (k * 256 + t) * 4;
            float4 v = *(const float4*)(src + f);
            const int di = f >> 10, m = (f >> 5) & 31, j = f & 31;
            H4 hv;
            hv.e[0] = (_Float16)v.x; hv.e[1] = (_Float16)v.y;
            hv.e[2] = (_Float16)v.z; hv.e[3] = (_Float16)v.w;
            *(uint2*)(lg + di * 1152 + m * 36 + j) = make_uint2(hv.u[0], hv.u[1]);
        }
        __syncthreads();
#pragma unroll
        for (int k = 0; k < 8; ++k) {         // coalesced 16B fragment writes
            const int idx = k * 256 + t;
            const int tl = idx >> 6, ln = idx & 63;
            const int di = tl >> 1, jh = tl & 1;
            const int q = ln >> 4, j4 = ln & 15;
            const int j = jh * 16 + j4;
            H8 o;
#pragma unroll
            for (int r = 0; r < 8; ++r)
                o.e[r] = lg[di * 1152 + (8 * q + r) * 36 + j];
            const size_t gi = ((size_t)(c * DD + d) * 64 + hf * 32 + tl) * 64 + ln;
            *(v8h*)(gh + gi * 8) = o.h;
        }
    }
}

// ---------------------------------------------------------------------------
// Kernel 2: per (c, b-block of 16, segment s): build 16 cores per d via MFMA,
// 2 chains per wave, G fragments prefetched one d ahead.
// XCD swizzle (bid%8 heuristic): class c's 64 blocks land on one XCD so its
// ~2 MB gh working set stays L2-resident (r8 lesson: 640 MB of L3-side G
// re-reads was the chain bottleneck). c=8 split over XCD 2..5, c=9 over
// {6,7,0,1} -> exactly 80 blocks per XCD.
// ---------------------------------------------------------------------------
__global__ __launch_bounds__(512, 4) void chain_kernel(
    const _Float16* __restrict__ feat_h,
    const _Float16* __restrict__ g_h,
    float* __restrict__ segP)          // [2][C][B][32][32] fp32, s=1 transposed
{
    __shared__ __align__(16) _Float16 lds[BBLK * BREGH];  // 41728 B

    const int bid = blockIdx.x;        // 0..639
    const int xcd = bid & 7;
    const int idx = bid >> 3;          // 0..79
    int c, sub;
    if (idx < 64) { c = xcd; sub = idx; }
    else {
        const int e = idx - 64;        // 0..15
        if (xcd >= 2 && xcd <= 5) { c = 8; sub = (xcd - 2) * 16 + e; }
        else                      { c = 9; sub = (((xcd + 2) & 7)) * 16 + e; }
    }
    const int s  = sub & 1;
    const int b0 = (sub >> 1) * BBLK;
    const int d0 = s * DSEG;
    const int t    = threadIdx.x;
    const int w    = t >> 6;           // wave 0..7
    const int lane = t & 63;
    const int q    = lane >> 4;
    const int j4   = lane & 15;

    const int bA = b0 + j4;            // all 16 A rows valid
    const size_t gc = (size_t)c * DD * 32768;

    // prefetch d0 fragments
    v8h afh = *(const v8h*)(feat_h + (size_t)bA * (DD * MM) + d0 * MM + q * 8);
    v8h gf[8];
#pragma unroll
    for (int u = 0; u < 8; ++u)
        gf[u] = *(const v8h*)(g_h + gc + (size_t)d0 * 32768 +
                              ((size_t)(w * 8 + u) * 64 + lane) * 8);

    v8h pah[2][2];                     // [chain cc][mi]

    for (int dd = 0; dd < DSEG; ++dd) {
        const int d = d0 + dd;
        __syncthreads();   // WAR: previous p2 reads of lds done
        // ---- phase 1: 8 MFMAs on prefetched fragments --------------------
        v4f av[8];
#pragma unroll
        for (int u = 0; u < 8; ++u) {
            v4f z = {0.f, 0.f, 0.f, 0.f};
            av[u] = __builtin_amdgcn_mfma_f32_16x16x32_f16(afh, gf[u], z, 0, 0, 0);
        }
        if (dd < DSEG - 1) {           // prefetch d+1 (overlaps p2 + barriers)
            afh = *(const v8h*)(feat_h + (size_t)bA * (DD * MM) + (d + 1) * MM + q * 8);
            const size_t gb = gc + (size_t)(d + 1) * 32768;
#pragma unroll
            for (int u = 0; u < 8; ++u)
                gf[u] = *(const v8h*)(g_h + gb + ((size_t)(w * 8 + u) * 64 + lane) * 8);
        }
        // store cores: L[b=4q+reg][j][i], i = 4w+ii contiguous
#pragma unroll
        for (int jh = 0; jh < 2; ++jh)
#pragma unroll
            for (int reg = 0; reg < 4; ++reg) {
                H4 hv;
                hv.e[0] = (_Float16)av[0 + jh][reg];
                hv.e[1] = (_Float16)av[2 + jh][reg];
                hv.e[2] = (_Float16)av[4 + jh][reg];
                hv.e[3] = (_Float16)av[6 + jh][reg];
                *(uint2*)(&lds[(4 * q + reg) * BREGH + (16 * jh + j4) * ROWH + 4 * w]) =
                    make_uint2(hv.u[0], hv.u[1]);
            }
        __syncthreads();   // cores ready
        // ---- phase 2: wave w advances chains b = 2w, 2w+1 ----------------
#pragma unroll
        for (int cc = 0; cc < 2; ++cc) {
            const int bl = 2 * w + cc;
            _Float16* base = lds + bl * BREGH;
            if (dd == 0) {
#pragma unroll
                for (int mi = 0; mi < 2; ++mi) {
                    H8 a;
#pragma unroll
                    for (int r = 0; r < 8; ++r)
                        a.e[r] = base[(8 * q + r) * ROWH + 16 * mi + j4];
                    pah[cc][mi] = a.h;
                }
            } else {
                v8h bf[2];
#pragma unroll
                for (int ni = 0; ni < 2; ++ni)
                    bf[ni] = *(const v8h*)(base + (16 * ni + j4) * ROWH + 8 * q);
                v4f acc[2][2];
#pragma unroll
                for (int mi = 0; mi < 2; ++mi)
#pragma unroll
                    for (int ni = 0; ni < 2; ++ni) {
                        v4f z = {0.f, 0.f, 0.f, 0.f};
                        acc[mi][ni] = __builtin_amdgcn_mfma_f32_16x16x32_f16(
                            pah[cc][mi], bf[ni], z, 0, 0, 0);
                    }
                if (dd < DSEG - 1) {
#pragma unroll
                    for (int mi = 0; mi < 2; ++mi)
#pragma unroll
                        for (int ni = 0; ni < 2; ++ni)
#pragma unroll
                            for (int reg = 0; reg < 4; ++reg)
                                base[(16 * mi + 4 * q + reg) * ROWH + 16 * ni + j4] =
                                    (_Float16)acc[mi][ni][reg];
                    __builtin_amdgcn_sched_barrier(0);
#pragma unroll
                    for (int mi = 0; mi < 2; ++mi)
                        pah[cc][mi] = *(const v8h*)(base + (16 * mi + j4) * ROWH + 8 * q);
                } else {
                    // final segment product, fp32; s=1 stored transposed
                    float* dst = segP + ((size_t)s * CC * BB +
                                         (size_t)c * BB + (b0 + bl)) * 1024;
                    if (s == 0) {
#pragma unroll
                        for (int mi = 0; mi < 2; ++mi)
#pragma unroll
                            for (int ni = 0; ni < 2; ++ni)
#pragma unroll
                                for (int reg = 0; reg < 4; ++reg)
                                    dst[(16 * mi + 4 * q + reg) * 32 + 16 * ni + j4] =
                                        acc[mi][ni][reg];
                    } else {
#pragma unroll
                        for (int mi = 0; mi < 2; ++mi)
#pragma unroll
                            for (int ni = 0; ni < 2; ++ni)
#pragma unroll
                                for (int reg = 0; reg < 4; ++reg)
                                    dst[(16 * ni + j4) * 32 + 16 * mi + 4 * q + reg] =
                                        acc[mi][ni][reg];
                    }
                }
            }
        }
    }
}

// ---------------------------------------------------------------------------
// Kernel 3: fused combine + log-softmax. Wave per b:
//   tr[c] = sum_ij P0[i][j] * P1[j][i]  (P1 pre-transposed -> pure dot)
// ---------------------------------------------------------------------------
__global__ __launch_bounds__(256) void combine_lsm_kernel(
    const float* __restrict__ segP, float* __restrict__ out) {
    const int t    = threadIdx.x;
    const int b    = blockIdx.x * 4 + (t >> 6);
    const int lane = t & 63;
    const float* P1b = segP + (size_t)CC * BB * 1024;

    float tr[CC];
#pragma unroll
    for (int c = 0; c < CC; ++c) {
        const float* p0 = segP + ((size_t)c * BB + b) * 1024 + lane * 16;
        const float* p1 = P1b  + ((size_t)c * BB + b) * 1024 + lane * 16;
        float acc = 0.f;
#pragma unroll
        for (int v = 0; v < 4; ++v) {
            float4 x = ((const float4*)p0)[v];
            float4 y = ((const float4*)p1)[v];
            acc += x.x * y.x + x.y * y.y + x.z * y.z + x.w * y.w;
        }
#pragma unroll
        for (int off = 32; off > 0; off >>= 1)
            acc += __shfl_xor(acc, off);
        tr[c] = acc;
    }
    float mx = -1e30f;
#pragma unroll
    for (int c = 0; c < CC; ++c) mx = fmaxf(mx, tr[c]);
    float ssum = 0.f;
#pragma unroll
    for (int c = 0; c < CC; ++c) ssum += expf(tr[c] - mx);
    const float ls = logf(ssum);
    float val = 0.f;
#pragma unroll
    for (int c = 0; c < CC; ++c) if (lane == c) val = tr[c] - mx - ls;
    if (lane < CC) out[b * CC + lane] = val;
}

// ---------------------------------------------------------------------------
extern "C" void kernel_launch(void* const* d_in, const int* in_sizes, int n_in,
                              void* d_out, int out_size, void* d_ws, size_t ws_size,
                              hipStream_t stream) {
    const float* tensor = (const float*)d_in[0];
    const float* W      = (const float*)d_in[1];
    const float* bias   = (const float*)d_in[2];
    const float* G      = (const float*)d_in[3];
    float* out = (float*)d_out;

    const size_t FEAT = (size_t)BB * DD * MM;          // 262144 halves
    const size_t GPK  = (size_t)CC * DD * 64 * 64 * 8; // 5242880 halves
    _Float16* fh = (_Float16*)d_ws;
    _Float16* gh = fh + FEAT;
    float* segP  = (float*)(gh + GPK);                 // 2*10*512*1024 floats (40 MB)

    produce_kernel<<<1024 + 320, 256, 0, stream>>>(tensor, W, bias, G, fh, gh);
    chain_kernel<<<CC * (BB / BBLK) * SS, 512, 0, stream>>>(fh, gh, segP);
    combine_lsm_kernel<<<BB / 4, 256, 0, stream>>>(segP, out);
}